// Round 5
// baseline (567.256 us; speedup 1.0000x reference)
//
#include <hip/hip_runtime.h>
#include <hip/hip_cooperative_groups.h>
#include <math.h>

namespace cg = cooperative_groups;

#define DIM 512
#define NROWS 50000
#define NORM 0.04419417382415922f   // 1/sqrt(512)

#define BLOCKS 1792                 // 7 blocks/CU x 256 CU (co-resident)
#define THREADS 256
#define QPART_BLOCKS 32             // 16 rows of W_query each
#define V_BLOCKS 128                // 4 rows of W_key each (wave-per-row)

// Fallback (non-cooperative) path sizes
#define FB_QP_BLOCKS 64
#define FB_CP_BLOCKS 2048

// out layout (floats): [0,512) q_max | [512] attn_max | [513] log_attn_max
//                      | [514,1026) concat | [1026,51026) maskf | [51026] max_indx
#define OUT_ATTN 512
#define OUT_LOG  513
#define OUT_IDX  51026
// Final 128B line of out covers floats [51008,51040): maskf indices i>=49982
// plus OUT_IDX. Single-writer rule: only block 0 (phase 3) touches that line.
#define MASKF_SPLIT 49982

// ws layout (floats):
// [0,16384) qpart (32x512) | [16384,16896) v | [16896,19200) pm (2304)
// [19200,21504) ps | [21504,23808) pidx(int) | [23808,73808) compat

__device__ inline float dot4(float4 a, float4 b, float acc) {
    acc = fmaf(a.x, b.x, acc);
    acc = fmaf(a.y, b.y, acc);
    acc = fmaf(a.z, b.z, acc);
    acc = fmaf(a.w, b.w, acc);
    return acc;
}

// online-softmax + first-occurrence argmax combine (associative)
__device__ inline void sm_combine(float& m, float& s, int& idx,
                                  float m2, float s2, int idx2) {
    bool take2 = (m2 > m) || (m2 == m && idx2 < idx);
    float hm = take2 ? m2 : m;
    float hs = take2 ? s2 : s;
    int   hi = take2 ? idx2 : idx;
    float lm = take2 ? m : m2;
    float ls = take2 ? s : s2;
    if (lm > -INFINITY) hs = fmaf(ls, expf(lm - hm), hs);
    m = hm; s = hs; idx = hi;
}

// ======================= fused cooperative kernel =======================
__global__ __launch_bounds__(THREADS, 7) void fused_kernel(
    const float* __restrict__ q, const float* __restrict__ l,
    const float* __restrict__ ctx, const float* __restrict__ g,
    const int* __restrict__ mask, const int* __restrict__ is_random,
    const long long* __restrict__ rnet,
    const float* __restrict__ Wc, const float* __restrict__ Wg,
    const float* __restrict__ Wq, const float* __restrict__ Wk,
    float* __restrict__ out, float* __restrict__ qpart,
    float* __restrict__ v, float* __restrict__ pm, float* __restrict__ ps,
    int* __restrict__ pidx, float* __restrict__ compat) {
    cg::grid_group grid = cg::this_grid();
    int t = threadIdx.x;
    int b = blockIdx.x;

    __shared__ __align__(16) float shf[DIM];     // gctx (P0) then Q (P1)
    __shared__ float red_m[THREADS], red_s[THREADS];
    __shared__ int red_i[THREADS];

    // ---------------- Phase 0: maskf copy + qpart partials ----------------
    float* out_maskf = out + 1026;
    for (int i = b * THREADS + t; i < MASKF_SPLIT; i += BLOCKS * THREADS)
        out_maskf[i] = (float)mask[i];

    if (b < QPART_BLOCKS) {
        float wc0 = Wc[0], wc1 = Wc[1], wg0 = Wg[0], wg1 = Wg[1];
        for (int j = t; j < DIM; j += THREADS) {
            float cc = wc0 * l[j] + wc1 * ctx[j];
            if (b == 0) out[514 + j] = cc;       // concat output
            shf[j] = wg0 * g[j] + wg1 * cc;
        }
        __syncthreads();
        int d0 = b * 16;
        float acc0 = 0.f, acc1 = 0.f;
        for (int d = d0; d < d0 + 16; ++d) {
            float gd = shf[d];
            acc0 = fmaf(gd, Wq[d * DIM + t], acc0);
            acc1 = fmaf(gd, Wq[d * DIM + t + 256], acc1);
        }
        qpart[b * DIM + t] = acc0;
        qpart[b * DIM + t + 256] = acc1;
    }

    grid.sync();

    // ---------------- Phase 1: v = W_key @ Q ----------------
    if (b < V_BLOCKS) {
        for (int j = t; j < DIM; j += THREADS) {
            float a = 0.f;
            for (int p = 0; p < QPART_BLOCKS; ++p) a += qpart[p * DIM + j];
            shf[j] = a;
        }
        __syncthreads();
        int lane = t & 63;
        int w = t >> 6;
        int r = b * 4 + w;
        const float4* row = (const float4*)(Wk + (size_t)r * DIM);
        const float4* qv = (const float4*)shf;
        float4 a0 = row[lane],  a1 = row[lane + 64];
        float4 b0 = qv[lane],   b1 = qv[lane + 64];
        float d = dot4(a1, b1, dot4(a0, b0, 0.f));
        #pragma unroll
        for (int off = 32; off > 0; off >>= 1) d += __shfl_xor(d, off);
        if (lane == 0) v[r] = d;
    }

    grid.sync();

    // ---------------- Phase 2: compat + per-block online-softmax ----------
    {
        int gtid = b * THREADS + t;
        int lane = t & 63;
        int wid = gtid >> 6;
        int nw = (BLOCKS * THREADS) >> 6;        // 7168 waves

        const float4* vv = (const float4*)v;
        float4 b0 = vv[lane];
        float4 b1 = vv[lane + 64];

        float m = -INFINITY, s = 0.f;
        int idx = 0x7fffffff;

        for (int n = wid; n < NROWS; n += nw) {
            if (mask[n] == 0) {                  // wave-uniform branch
                if (lane == 0) compat[n] = -INFINITY;
                continue;                        // skip the 2KB row read
            }
            const float4* row = (const float4*)(q + (size_t)n * DIM);
            float4 a0 = row[lane];
            float4 a1 = row[lane + 64];
            float d = dot4(a1, b1, dot4(a0, b0, 0.f));
            #pragma unroll
            for (int off = 32; off > 0; off >>= 1) d += __shfl_xor(d, off);
            float c = tanhf(NORM * d) * 10.0f;
            if (lane == 0) compat[n] = c;
            sm_combine(m, s, idx, c, 1.0f, n);
        }

        int w = t >> 6;
        if (lane == 0) { red_m[w] = m; red_s[w] = s; red_i[w] = idx; }
        __syncthreads();
        if (t == 0) {
            float M = red_m[0], S = red_s[0];
            int I = red_i[0];
            for (int i = 1; i < THREADS / 64; ++i)
                sm_combine(M, S, I, red_m[i], red_s[i], red_i[i]);
            pm[b] = M;
            ps[b] = S;
            pidx[b] = I;
        }
        __syncthreads();
    }

    grid.sync();

    // ---------------- Phase 3: finalize (block 0 only) ----------------
    if (b == 0) {
        // single-writer tail line: maskf[49982..50000) + OUT_IDX
        if (t < NROWS - MASKF_SPLIT)
            out_maskf[MASKF_SPLIT + t] = (float)mask[MASKF_SPLIT + t];

        float m = -INFINITY, s = 0.f;
        int idx = 0x7fffffff;
        for (int i = t; i < BLOCKS; i += THREADS)
            sm_combine(m, s, idx, pm[i], ps[i], pidx[i]);
        red_m[t] = m; red_s[t] = s; red_i[t] = idx;
        __syncthreads();
        for (int off = THREADS / 2; off > 0; off >>= 1) {
            if (t < off) {
                float M = red_m[t], S = red_s[t];
                int I = red_i[t];
                sm_combine(M, S, I, red_m[t + off], red_s[t + off], red_i[t + off]);
                red_m[t] = M; red_s[t] = S; red_i[t] = I;
            }
            __syncthreads();
        }
        __shared__ int chosen;
        if (t == 0) {
            float M = red_m[0], S = red_s[0];
            int ix = red_i[0];
            if (is_random[0] != 0) ix = (int)rnet[0];
            float c = compat[ix];
            __hip_atomic_store(&out[OUT_ATTN], expf(c - M) / S,
                               __ATOMIC_RELAXED, __HIP_MEMORY_SCOPE_AGENT);
            __hip_atomic_store(&out[OUT_LOG], (c - M) - logf(S),
                               __ATOMIC_RELAXED, __HIP_MEMORY_SCOPE_AGENT);
            __hip_atomic_store(&out[OUT_IDX], (float)ix,
                               __ATOMIC_RELAXED, __HIP_MEMORY_SCOPE_AGENT);
            chosen = ix;
        }
        __syncthreads();
        out[t]       = q[(size_t)chosen * DIM + t];
        out[t + 256] = q[(size_t)chosen * DIM + t + 256];
    }
}

// ======================= fallback path (round-3 proven) =======================
__global__ __launch_bounds__(256) void qpart_kernel(
    const float* __restrict__ l, const float* __restrict__ ctx,
    const float* __restrict__ g, const float* __restrict__ Wc,
    const float* __restrict__ Wg, const float* __restrict__ Wq,
    const int* __restrict__ mask,
    float* __restrict__ qpart, float* __restrict__ out_concat,
    float* __restrict__ out_maskf) {
    int t = threadIdx.x;
    int b = blockIdx.x;
    for (int i = b * 256 + t; i < NROWS; i += FB_QP_BLOCKS * 256)
        out_maskf[i] = (float)mask[i];
    if (b >= QPART_BLOCKS) return;

    __shared__ float gctx[DIM];
    float wc0 = Wc[0], wc1 = Wc[1], wg0 = Wg[0], wg1 = Wg[1];
    for (int j = t; j < DIM; j += 256) {
        float cc = wc0 * l[j] + wc1 * ctx[j];
        if (b == 0) out_concat[j] = cc;
        gctx[j] = wg0 * g[j] + wg1 * cc;
    }
    __syncthreads();
    int d0 = b * 16;
    float acc0 = 0.f, acc1 = 0.f;
    for (int d = d0; d < d0 + 16; ++d) {
        float gd = gctx[d];
        acc0 = fmaf(gd, Wq[d * DIM + t], acc0);
        acc1 = fmaf(gd, Wq[d * DIM + t + 256], acc1);
    }
    qpart[b * DIM + t] = acc0;
    qpart[b * DIM + t + 256] = acc1;
}

__global__ __launch_bounds__(256) void v_kernel(
    const float* __restrict__ Wk, const float* __restrict__ qpart,
    float* __restrict__ v) {
    __shared__ __align__(16) float Q[DIM];
    int t = threadIdx.x;
    for (int j = t; j < DIM; j += 256) {
        float a = 0.f;
        for (int p = 0; p < QPART_BLOCKS; ++p) a += qpart[p * DIM + j];
        Q[j] = a;
    }
    __syncthreads();
    int lane = t & 63;
    int w = t >> 6;
    int r = blockIdx.x * 4 + w;
    const float4* row = (const float4*)(Wk + (size_t)r * DIM);
    const float4* qv = (const float4*)Q;
    float4 a0 = row[lane],      a1 = row[lane + 64];
    float4 b0 = qv[lane],       b1 = qv[lane + 64];
    float d = dot4(a1, b1, dot4(a0, b0, 0.f));
    #pragma unroll
    for (int off = 32; off > 0; off >>= 1) d += __shfl_xor(d, off);
    if (lane == 0) v[r] = d;
}

__global__ __launch_bounds__(256) void compat_kernel(
    const float* __restrict__ q, const int* __restrict__ mask,
    const float* __restrict__ v, float* __restrict__ compat,
    float* __restrict__ pm, float* __restrict__ ps, int* __restrict__ pidx) {
    int t = threadIdx.x;
    int gtid = blockIdx.x * 256 + t;
    int gsz = FB_CP_BLOCKS * 256;

    int lane = t & 63;
    int wid = gtid >> 6;
    int nw = gsz >> 6;

    const float4* vv = (const float4*)v;
    float4 b0 = vv[lane];
    float4 b1 = vv[lane + 64];

    float m = -INFINITY, s = 0.f;
    int idx = 0x7fffffff;

    for (int n = wid; n < NROWS; n += nw) {
        if (mask[n] == 0) {
            if (lane == 0) compat[n] = -INFINITY;
            continue;
        }
        const float4* row = (const float4*)(q + (size_t)n * DIM);
        float4 a0 = row[lane];
        float4 a1 = row[lane + 64];
        float d = dot4(a1, b1, dot4(a0, b0, 0.f));
        #pragma unroll
        for (int off = 32; off > 0; off >>= 1) d += __shfl_xor(d, off);
        float c = tanhf(NORM * d) * 10.0f;
        if (lane == 0) compat[n] = c;
        sm_combine(m, s, idx, c, 1.0f, n);
    }

    __shared__ float bm[4], bs[4];
    __shared__ int bidx[4];
    int w = t >> 6;
    if (lane == 0) { bm[w] = m; bs[w] = s; bidx[w] = idx; }
    __syncthreads();
    if (t == 0) {
        float M = bm[0], S = bs[0];
        int I = bidx[0];
        for (int i = 1; i < 4; ++i)
            sm_combine(M, S, I, bm[i], bs[i], bidx[i]);
        pm[blockIdx.x] = M;
        ps[blockIdx.x] = S;
        pidx[blockIdx.x] = I;
    }
}

__global__ __launch_bounds__(512) void finalize_kernel(
    const float* __restrict__ q, const float* __restrict__ pm,
    const float* __restrict__ ps, const int* __restrict__ pidx,
    const float* __restrict__ compat, const int* __restrict__ is_random,
    const long long* __restrict__ rnet, float* __restrict__ out) {
    __shared__ float sm[512], ss[512];
    __shared__ int si[512];
    __shared__ int chosen;
    int t = threadIdx.x;
    float m = -INFINITY, s = 0.f;
    int idx = 0x7fffffff;
    for (int i = t; i < FB_CP_BLOCKS; i += 512)
        sm_combine(m, s, idx, pm[i], ps[i], pidx[i]);
    sm[t] = m; ss[t] = s; si[t] = idx;
    __syncthreads();
    for (int off = 256; off > 0; off >>= 1) {
        if (t < off) {
            float M = sm[t], S = ss[t];
            int I = si[t];
            sm_combine(M, S, I, sm[t + off], ss[t + off], si[t + off]);
            sm[t] = M; ss[t] = S; si[t] = I;
        }
        __syncthreads();
    }
    if (t == 0) {
        float M = sm[0], S = ss[0];
        int ix = si[0];
        if (is_random[0] != 0) ix = (int)rnet[0];
        float c = compat[ix];
        out[OUT_ATTN] = expf(c - M) / S;
        out[OUT_LOG]  = (c - M) - logf(S);
        out[OUT_IDX]  = (float)ix;
        chosen = ix;
    }
    __syncthreads();
    out[t] = q[(size_t)chosen * DIM + t];
}

extern "C" void kernel_launch(void* const* d_in, const int* in_sizes, int n_in,
                              void* d_out, int out_size, void* d_ws, size_t ws_size,
                              hipStream_t stream) {
    const float*     q    = (const float*)d_in[0];
    const float*     l    = (const float*)d_in[1];
    const float*     ctx  = (const float*)d_in[2];
    const float*     g    = (const float*)d_in[3];
    const int*       mask = (const int*)d_in[4];
    const int*       isr  = (const int*)d_in[5];
    const long long* rnet = (const long long*)d_in[6];
    const float*     Wc   = (const float*)d_in[7];
    const float*     Wg   = (const float*)d_in[8];
    const float*     Wq   = (const float*)d_in[9];
    const float*     Wk   = (const float*)d_in[10];

    float* out = (float*)d_out;
    float* ws  = (float*)d_ws;
    float* qpart  = ws;
    float* v      = ws + 16384;
    float* pm     = ws + 16896;
    float* ps     = ws + 19200;
    int*   pidx   = (int*)(ws + 21504);
    float* compat = ws + 23808;

    void* args[] = {
        (void*)&q, (void*)&l, (void*)&ctx, (void*)&g, (void*)&mask,
        (void*)&isr, (void*)&rnet, (void*)&Wc, (void*)&Wg, (void*)&Wq,
        (void*)&Wk, (void*)&out, (void*)&qpart, (void*)&v, (void*)&pm,
        (void*)&ps, (void*)&pidx, (void*)&compat
    };
    hipError_t rc = hipLaunchCooperativeKernel((const void*)fused_kernel,
                                               dim3(BLOCKS), dim3(THREADS),
                                               args, 0, stream);
    if (rc != hipSuccess) {
        // Deterministic fallback: proven 4-kernel pipeline (identical math).
        qpart_kernel<<<FB_QP_BLOCKS, 256, 0, stream>>>(l, ctx, g, Wc, Wg, Wq,
                                                       mask, qpart, out + 514,
                                                       out + 1026);
        v_kernel<<<V_BLOCKS, 256, 0, stream>>>(Wk, qpart, v);
        compat_kernel<<<FB_CP_BLOCKS, 256, 0, stream>>>(q, mask, v, compat,
                                                        pm, ps, pidx);
        finalize_kernel<<<1, 512, 0, stream>>>(q, pm, ps, pidx, compat,
                                               isr, rnet, out);
    }
}

// Round 6
// 32.587 us; speedup vs baseline: 17.4073x; 17.4073x over previous
//
#include <hip/hip_runtime.h>
#include <math.h>

#define DIM 512
#define NROWS 50000
#define NORM 0.04419417382415922f   // 1/sqrt(512)

#define QP_BLOCKS 64                // 8 rows of W_query each + maskf copy
#define V_BLOCKS 128                // 4 rows of W_key each (wave-per-row)
#define CP_BLOCKS 2048              // 8192 waves = full occupancy
#define CP_THREADS 256

// out layout (floats): [0,512) q_max | [512] attn_max | [513] log_attn_max
//                      | [514,1026) concat | [1026,51026) maskf | [51026] max_indx
#define OUT_ATTN 512
#define OUT_LOG  513
#define OUT_IDX  51026

// ws layout (floats):
// [0,32768) qpart (64x512) | [32768,33280) v | [33280,35328) pm
// [35328,37376) ps | [37376,39424) pidx(int) | [39424,89424) compat

__device__ inline float dot4(float4 a, float4 b, float acc) {
    acc = fmaf(a.x, b.x, acc);
    acc = fmaf(a.y, b.y, acc);
    acc = fmaf(a.z, b.z, acc);
    acc = fmaf(a.w, b.w, acc);
    return acc;
}

// online-softmax + first-occurrence argmax combine (associative)
__device__ inline void sm_combine(float& m, float& s, int& idx,
                                  float m2, float s2, int idx2) {
    bool take2 = (m2 > m) || (m2 == m && idx2 < idx);
    float hm = take2 ? m2 : m;
    float hs = take2 ? s2 : s;
    int   hi = take2 ? idx2 : idx;
    float lm = take2 ? m : m2;
    float ls = take2 ? s : s2;
    if (lm > -INFINITY) hs = fmaf(ls, __expf(lm - hm), hs);
    m = hm; s = hs; idx = hi;
}

// Stage 1: concat, g_context, split-K partials of Q = g_context @ W_query
// (8 d-rows per block), plus mask -> float copy.
__global__ __launch_bounds__(256) void qpart_kernel(
    const float* __restrict__ l, const float* __restrict__ ctx,
    const float* __restrict__ g, const float* __restrict__ Wc,
    const float* __restrict__ Wg, const float* __restrict__ Wq,
    const int* __restrict__ mask,
    float* __restrict__ qpart, float* __restrict__ out_concat,
    float* __restrict__ out_maskf) {
    int t = threadIdx.x;
    int b = blockIdx.x;
    for (int i = b * 256 + t; i < NROWS; i += QP_BLOCKS * 256)
        out_maskf[i] = (float)mask[i];

    __shared__ float gctx[DIM];
    float wc0 = Wc[0], wc1 = Wc[1], wg0 = Wg[0], wg1 = Wg[1];
    for (int j = t; j < DIM; j += 256) {
        float cc = wc0 * l[j] + wc1 * ctx[j];
        if (b == 0) out_concat[j] = cc;
        gctx[j] = wg0 * g[j] + wg1 * cc;
    }
    __syncthreads();
    int d0 = b * 8;
    float acc0 = 0.f, acc1 = 0.f;
    #pragma unroll
    for (int d = 0; d < 8; ++d) {
        float gd = gctx[d0 + d];
        acc0 = fmaf(gd, Wq[(d0 + d) * DIM + t], acc0);
        acc1 = fmaf(gd, Wq[(d0 + d) * DIM + t + 256], acc1);
    }
    qpart[b * DIM + t] = acc0;
    qpart[b * DIM + t + 256] = acc1;
}

// Stage 2: reduce Q partials (fixed order) then v[r] = W_key[r,:] . Q
__global__ __launch_bounds__(256) void v_kernel(
    const float* __restrict__ Wk, const float* __restrict__ qpart,
    float* __restrict__ v) {
    __shared__ __align__(16) float Q[DIM];
    int t = threadIdx.x;
    for (int j = t; j < DIM; j += 256) {
        float a = 0.f;
        for (int p = 0; p < QP_BLOCKS; ++p) a += qpart[p * DIM + j];
        Q[j] = a;
    }
    __syncthreads();
    int lane = t & 63;
    int w = t >> 6;
    int r = blockIdx.x * 4 + w;
    const float4* row = (const float4*)(Wk + (size_t)r * DIM);
    const float4* qv = (const float4*)Q;
    float4 a0 = row[lane],      a1 = row[lane + 64];
    float4 b0 = qv[lane],       b1 = qv[lane + 64];
    float d = dot4(a1, b1, dot4(a0, b0, 0.f));
    #pragma unroll
    for (int off = 32; off > 0; off >>= 1) d += __shfl_xor(d, off);
    if (lane == 0) v[r] = d;
}

// Stage 3: compat[n] = tanh(norm * q[n].v)*10; 2 rows/wave (32-lane groups),
// fast tanh via native exp2/rcp, mask prefetch; per-block softmax partial.
__global__ __launch_bounds__(CP_THREADS) void compat_kernel(
    const float* __restrict__ q, const int* __restrict__ mask,
    const float* __restrict__ v, float* __restrict__ compat,
    float* __restrict__ pm, float* __restrict__ ps, int* __restrict__ pidx) {
    int t = threadIdx.x;
    int lane = t & 63;
    int w = t >> 6;
    int g = lane >> 5;              // row-group 0..1 within wave
    int gl = lane & 31;             // lane within group
    int wid = (blockIdx.x << 2) + w;
    const int nw = CP_BLOCKS * 4;   // 8192 waves

    // v fragment: lane gl covers floats [gl*16, gl*16+16)
    const float4* vv = (const float4*)v;
    float4 vf0 = vv[gl * 4 + 0], vf1 = vv[gl * 4 + 1];
    float4 vf2 = vv[gl * 4 + 2], vf3 = vv[gl * 4 + 3];

    float m = -INFINITY, s = 0.f;
    int idx = 0x7fffffff;

    int base = wid * 2;
    int mk = (base + g < NROWS) ? mask[base + g] : 0;
    for (; base < NROWS; base += nw * 2) {
        int nxt = base + nw * 2;
        int mknext = (nxt + g < NROWS) ? mask[nxt + g] : 0;   // prefetch
        int n = base + g;
        if (mk) {
            const float4* row = (const float4*)(q + (size_t)n * DIM);
            float4 a0 = row[gl * 4 + 0];
            float4 a1 = row[gl * 4 + 1];
            float4 a2 = row[gl * 4 + 2];
            float4 a3 = row[gl * 4 + 3];
            float d = dot4(a0, vf0, 0.f);
            d = dot4(a1, vf1, d);
            d = dot4(a2, vf2, d);
            d = dot4(a3, vf3, d);
            #pragma unroll
            for (int off = 16; off >= 1; off >>= 1) d += __shfl_xor(d, off);
            // 10*tanh(x) = 10 - 20/(exp2(2x*log2e)+1); |x| <~ 1.5, safe
            float x = NORM * d;
            float u = __builtin_amdgcn_exp2f(x * 2.885390081777927f);
            float c = fmaf(-20.f, __builtin_amdgcn_rcpf(u + 1.f), 10.f);
            if (gl == 0) compat[n] = c;
            sm_combine(m, s, idx, c, 1.0f, n);
        } else if (n < NROWS) {
            if (gl == 0) compat[n] = -INFINITY;
        }
        mk = mknext;
    }

    __shared__ float bm[8], bs[8];
    __shared__ int bidx[8];
    if (gl == 0) { bm[w * 2 + g] = m; bs[w * 2 + g] = s; bidx[w * 2 + g] = idx; }
    __syncthreads();
    if (t == 0) {
        float M = bm[0], S = bs[0];
        int I = bidx[0];
        for (int i = 1; i < 8; ++i)
            sm_combine(M, S, I, bm[i], bs[i], bidx[i]);
        pm[blockIdx.x] = M;
        ps[blockIdx.x] = S;
        pidx[blockIdx.x] = I;
    }
}

// Stage 4: combine partials, write attn/log_attn/idx, copy q[idx].
__global__ __launch_bounds__(512) void finalize_kernel(
    const float* __restrict__ q, const float* __restrict__ pm,
    const float* __restrict__ ps, const int* __restrict__ pidx,
    const float* __restrict__ compat, const int* __restrict__ is_random,
    const long long* __restrict__ rnet, float* __restrict__ out) {
    __shared__ float sm[512], ss[512];
    __shared__ int si[512];
    __shared__ int chosen;
    int t = threadIdx.x;
    float m = -INFINITY, s = 0.f;
    int idx = 0x7fffffff;
    for (int i = t; i < CP_BLOCKS; i += 512)
        sm_combine(m, s, idx, pm[i], ps[i], pidx[i]);
    sm[t] = m; ss[t] = s; si[t] = idx;
    __syncthreads();
    for (int off = 256; off > 0; off >>= 1) {
        if (t < off) {
            float M = sm[t], S = ss[t];
            int I = si[t];
            sm_combine(M, S, I, sm[t + off], ss[t + off], si[t + off]);
            sm[t] = M; ss[t] = S; si[t] = I;
        }
        __syncthreads();
    }
    if (t == 0) {
        float M = sm[0], S = ss[0];
        int ix = si[0];
        if (is_random[0] != 0) ix = (int)rnet[0];
        float c = compat[ix];
        out[OUT_ATTN] = expf(c - M) / S;
        out[OUT_LOG]  = (c - M) - logf(S);
        out[OUT_IDX]  = (float)ix;
        chosen = ix;
    }
    __syncthreads();
    out[t] = q[(size_t)chosen * DIM + t];
}

extern "C" void kernel_launch(void* const* d_in, const int* in_sizes, int n_in,
                              void* d_out, int out_size, void* d_ws, size_t ws_size,
                              hipStream_t stream) {
    const float*     q    = (const float*)d_in[0];
    const float*     l    = (const float*)d_in[1];
    const float*     ctx  = (const float*)d_in[2];
    const float*     g    = (const float*)d_in[3];
    const int*       mask = (const int*)d_in[4];
    const int*       isr  = (const int*)d_in[5];
    const long long* rnet = (const long long*)d_in[6];
    const float*     Wc   = (const float*)d_in[7];
    const float*     Wg   = (const float*)d_in[8];
    const float*     Wq   = (const float*)d_in[9];
    const float*     Wk   = (const float*)d_in[10];

    float* out = (float*)d_out;
    float* ws  = (float*)d_ws;
    float* qpart  = ws;
    float* v      = ws + 32768;
    float* pm     = ws + 33280;
    float* ps     = ws + 35328;
    int*   pidx   = (int*)(ws + 37376);
    float* compat = ws + 39424;

    qpart_kernel<<<QP_BLOCKS, 256, 0, stream>>>(l, ctx, g, Wc, Wg, Wq, mask,
                                                qpart, out + 514, out + 1026);
    v_kernel<<<V_BLOCKS, 256, 0, stream>>>(Wk, qpart, v);
    compat_kernel<<<CP_BLOCKS, CP_THREADS, 0, stream>>>(q, mask, v, compat,
                                                        pm, ps, pidx);
    finalize_kernel<<<1, 512, 0, stream>>>(q, pm, ps, pidx, compat,
                                           isr, rnet, out);
}